// Round 1
// baseline (2988.026 us; speedup 1.0000x reference)
//
#include <hip/hip_runtime.h>

// Problem constants (shapes are fixed by the reference; N,E,F derived from in_sizes at launch).
#define HD 256   // hidden dim H

static __device__ __forceinline__ float relu_f(float x){ return x > 0.f ? x : 0.f; }

// ---------------- CSR build ----------------
__global__ void k_count(const int* __restrict__ dst, int* __restrict__ cnt, int E){
    int i = blockIdx.x * blockDim.x + threadIdx.x;
    if (i < E) atomicAdd(&cnt[dst[i]], 1);
}

__global__ void k_dinv(const int* __restrict__ cnt, float* __restrict__ dinv, int n){
    int i = blockIdx.x * blockDim.x + threadIdx.x;
    if (i < n) dinv[i] = 1.0f / sqrtf((float)(cnt[i] + 1));   // +1 self loop; deg>=1 always
}

// single-block chunked Hillis-Steele exclusive scan (n ~ 20000, runs in ~µs)
__global__ void k_scan(const int* __restrict__ cnt, int* __restrict__ row_ptr, int n){
    __shared__ int lds[1024];
    int t = threadIdx.x;
    int carry = 0;
    for (int base = 0; base < n; base += 1024){
        int idx = base + t;
        int v = (idx < n) ? cnt[idx] : 0;
        __syncthreads();            // protect lds from previous chunk's readers
        lds[t] = v;
        __syncthreads();
        for (int off = 1; off < 1024; off <<= 1){
            int add = (t >= off) ? lds[t - off] : 0;
            __syncthreads();
            lds[t] += add;
            __syncthreads();
        }
        int incl = lds[t];
        if (idx < n) row_ptr[idx] = carry + incl - v;   // exclusive
        carry += lds[1023];
    }
    if (t == 0) row_ptr[n] = carry;   // == E
}

__global__ void k_fill(const int* __restrict__ src, const int* __restrict__ dst,
                       const int* __restrict__ row_ptr, int* __restrict__ fill,
                       int* __restrict__ csr_src, int* __restrict__ csr_dst, int E){
    int i = blockIdx.x * blockDim.x + threadIdx.x;
    if (i < E){
        int d = dst[i];
        int pos = row_ptr[d] + atomicAdd(&fill[d], 1);
        csr_src[pos] = src[i];
        csr_dst[pos] = d;
    }
}

// ---------------- dense node GEMM: C[M,256] = A[M,K] @ W[K,256] (+bias) ----------------
// BM=32, BN=256, BK=16, 256 threads. grid.x = M/32 (M divisible by 32).
__global__ __launch_bounds__(256) void k_gemm(const float* __restrict__ A,
                                              const float* __restrict__ W,
                                              const float* __restrict__ bias,
                                              float* __restrict__ C, int M, int K){
    __shared__ float As[16][36];     // [k][m], pad->36 floats (144B, 16B-aligned rows)
    __shared__ float Ws[16][HD];     // [k][n]
    int t = threadIdx.x;
    int m0 = blockIdx.x * 32;
    int tr = t >> 5, tc = t & 31;            // thread tile: rows tr*4+(0..3), cols tc*8+(0..7)
    int srow = t >> 3, skk = (t & 7) * 2;    // A staging: 32 rows x 16 k, float2 each
    int wkr = t >> 4, wc0 = (t & 15) * 16;   // W staging: 16 rows x 256, 4x float4 each

    float acc[4][8];
    #pragma unroll
    for (int i = 0; i < 4; i++)
        #pragma unroll
        for (int j = 0; j < 8; j++) acc[i][j] = 0.f;

    const float* Arow = A + (size_t)(m0 + srow) * K + skk;

    for (int k0 = 0; k0 < K; k0 += 16){
        float2 av = *(const float2*)(Arow + k0);
        As[skk][srow] = av.x;
        As[skk + 1][srow] = av.y;
        const float* wp = W + (size_t)(k0 + wkr) * HD + wc0;
        #pragma unroll
        for (int j = 0; j < 4; j++)
            *(float4*)&Ws[wkr][wc0 + 4 * j] = *(const float4*)(wp + 4 * j);
        __syncthreads();
        #pragma unroll
        for (int k = 0; k < 16; k++){
            float4 m4 = *(const float4*)&As[k][tr * 4];
            float4 wa = *(const float4*)&Ws[k][tc * 8];
            float4 wb = *(const float4*)&Ws[k][tc * 8 + 4];
            float mm[4] = {m4.x, m4.y, m4.z, m4.w};
            float ww[8] = {wa.x, wa.y, wa.z, wa.w, wb.x, wb.y, wb.z, wb.w};
            #pragma unroll
            for (int i = 0; i < 4; i++)
                #pragma unroll
                for (int j = 0; j < 8; j++) acc[i][j] += mm[i] * ww[j];
        }
        __syncthreads();
    }

    float bj[8];
    #pragma unroll
    for (int j = 0; j < 8; j++) bj[j] = bias ? bias[tc * 8 + j] : 0.f;
    #pragma unroll
    for (int i = 0; i < 4; i++){
        float* cp = C + (size_t)(m0 + tr * 4 + i) * HD + tc * 8;
        float4 o0 = {acc[i][0] + bj[0], acc[i][1] + bj[1], acc[i][2] + bj[2], acc[i][3] + bj[3]};
        float4 o1 = {acc[i][4] + bj[4], acc[i][5] + bj[5], acc[i][6] + bj[6], acc[i][7] + bj[7]};
        *(float4*)cp = o0;
        *(float4*)(cp + 4) = o1;
    }
}

// ---------------- GCN aggregate: out[i] = relu(dinv[i]*(sum_{e in(i)} h[s]*dinv[s] + h[i]*dinv[i]) + b) ----------------
// one wave per node, lane owns 4 of 256 dims. grid.x = N/4, 256 threads.
__global__ __launch_bounds__(256) void k_gcn_agg(const float* __restrict__ h,
                                                 const float* __restrict__ dinv,
                                                 const int* __restrict__ row_ptr,
                                                 const int* __restrict__ csr_src,
                                                 const float* __restrict__ bias,
                                                 float* __restrict__ out, int n){
    int wid = threadIdx.x >> 6, lane = threadIdx.x & 63;
    int i = blockIdx.x * 4 + wid;
    if (i >= n) return;
    float di = dinv[i];
    const float4* hp = (const float4*)h;
    float4 v = hp[(size_t)i * 64 + lane];
    float ax = v.x * di, ay = v.y * di, az = v.z * di, aw = v.w * di;  // self loop term
    int e0 = row_ptr[i], e1 = row_ptr[i + 1];
    for (int e = e0; e < e1; e++){
        int s = csr_src[e];
        float ds = dinv[s];
        float4 u = hp[(size_t)s * 64 + lane];
        ax += u.x * ds; ay += u.y * ds; az += u.z * ds; aw += u.w * ds;
    }
    const float4 b = ((const float4*)bias)[lane];
    float4 o;
    o.x = relu_f(ax * di + b.x);
    o.y = relu_f(ay * di + b.y);
    o.z = relu_f(az * di + b.z);
    o.w = relu_f(aw * di + b.w);
    ((float4*)out)[(size_t)i * 64 + lane] = o;
}

// ---------------- fused EdgeConv edge GEMM + max-aggregate ----------------
// per tile: 64 CSR-ordered edges x 256 outputs, K=256.
// msg[e] = relu(A[dst[e]] + B[src[e]]) built on the fly in LDS; C = msg @ W2 + b2;
// dst-grouped register max pre-reduction, then positive-only int-punned atomicMax into out (init 0).
__global__ __launch_bounds__(256) void k_edge(const float* __restrict__ A,
                                              const float* __restrict__ B,
                                              const float* __restrict__ W,
                                              const float* __restrict__ bias,
                                              const int* __restrict__ csr_src,
                                              const int* __restrict__ csr_dst,
                                              float* __restrict__ out){
    __shared__ float Ms[16][68];     // [k][edge-row], pad->68 (272B, 16B-aligned rows)
    __shared__ float Ws[16][HD];
    __shared__ int sdst[64], ssrc[64];
    int t = threadIdx.x;
    int p0 = blockIdx.x * 64;
    if (t < 64){
        sdst[t] = csr_dst[p0 + t];
        ssrc[t] = csr_src[p0 + t];
    }
    __syncthreads();

    int tr = t >> 5, tc = t & 31;            // thread tile: rows tr*8+(0..7), cols tc*8+(0..7)
    int srow = t >> 2, skk = (t & 3) * 4;    // msg staging: 64 rows x 16 k, float4 each
    int wkr = t >> 4, wc0 = (t & 15) * 16;
    size_t ga = (size_t)sdst[srow] * HD + skk;
    size_t gb = (size_t)ssrc[srow] * HD + skk;

    float acc[8][8];
    #pragma unroll
    for (int i = 0; i < 8; i++)
        #pragma unroll
        for (int j = 0; j < 8; j++) acc[i][j] = 0.f;

    for (int k0 = 0; k0 < HD; k0 += 16){
        float4 a = *(const float4*)(A + ga + k0);
        float4 b = *(const float4*)(B + gb + k0);
        Ms[skk + 0][srow] = relu_f(a.x + b.x);
        Ms[skk + 1][srow] = relu_f(a.y + b.y);
        Ms[skk + 2][srow] = relu_f(a.z + b.z);
        Ms[skk + 3][srow] = relu_f(a.w + b.w);
        const float* wp = W + (size_t)(k0 + wkr) * HD + wc0;
        #pragma unroll
        for (int j = 0; j < 4; j++)
            *(float4*)&Ws[wkr][wc0 + 4 * j] = *(const float4*)(wp + 4 * j);
        __syncthreads();
        #pragma unroll
        for (int k = 0; k < 16; k++){
            float4 ma = *(const float4*)&Ms[k][tr * 8];
            float4 mb = *(const float4*)&Ms[k][tr * 8 + 4];
            float4 wa = *(const float4*)&Ws[k][tc * 8];
            float4 wb = *(const float4*)&Ws[k][tc * 8 + 4];
            float m8[8] = {ma.x, ma.y, ma.z, ma.w, mb.x, mb.y, mb.z, mb.w};
            float w8[8] = {wa.x, wa.y, wa.z, wa.w, wb.x, wb.y, wb.z, wb.w};
            #pragma unroll
            for (int i = 0; i < 8; i++)
                #pragma unroll
                for (int j = 0; j < 8; j++) acc[i][j] += m8[i] * w8[j];
        }
        __syncthreads();
    }

    float bj[8];
    #pragma unroll
    for (int j = 0; j < 8; j++) bj[j] = bias[tc * 8 + j];

    int r0 = tr * 8;
    int curd = sdst[r0];
    float vm[8];
    #pragma unroll
    for (int j = 0; j < 8; j++) vm[j] = acc[0][j] + bj[j];
    #pragma unroll
    for (int i = 1; i < 8; i++){
        int d = sdst[r0 + i];
        if (d != curd){
            #pragma unroll
            for (int j = 0; j < 8; j++)
                if (vm[j] > 0.f)
                    atomicMax((int*)(out + (size_t)curd * HD + tc * 8 + j), __float_as_int(vm[j]));
            curd = d;
            #pragma unroll
            for (int j = 0; j < 8; j++) vm[j] = acc[i][j] + bj[j];
        } else {
            #pragma unroll
            for (int j = 0; j < 8; j++) vm[j] = fmaxf(vm[j], acc[i][j] + bj[j]);
        }
    }
    #pragma unroll
    for (int j = 0; j < 8; j++)
        if (vm[j] > 0.f)
            atomicMax((int*)(out + (size_t)curd * HD + tc * 8 + j), __float_as_int(vm[j]));
}

// ---------------- Wd = W_top - W_bot (EdgeConv linear decomposition) ----------------
__global__ void k_wdiff(const float* __restrict__ w, float* __restrict__ wd, int K){
    int i = blockIdx.x * blockDim.x + threadIdx.x;
    if (i < K * HD) wd[i] = w[i] - w[K * HD + i];
}

// ---------------- per-graph sum pool (batch is sorted; binary-search the range) ----------------
__global__ __launch_bounds__(512) void k_pool(const float* __restrict__ xg,
                                              const float* __restrict__ xe,
                                              const int* __restrict__ batch,
                                              float* __restrict__ gpool, int n){
    int g = blockIdx.x, t = threadIdx.x;
    int lo, hi;
    { int l = 0, h = n; while (l < h){ int m = (l + h) >> 1; if (batch[m] < g) l = m + 1; else h = m; } lo = l; }
    { int l = lo, h = n; while (l < h){ int m = (l + h) >> 1; if (batch[m] < g + 1) l = m + 1; else h = m; } hi = l; }
    const float* sp = (t < 256) ? (xg + t) : (xe + (t - 256));
    float a0 = 0.f, a1 = 0.f;
    int i = lo;
    for (; i + 1 < hi; i += 2){
        a0 += sp[(size_t)i * HD];
        a1 += sp[(size_t)(i + 1) * HD];
    }
    if (i < hi) a0 += sp[(size_t)i * HD];
    gpool[g * 512 + t] = a0 + a1;
}

// ---------------- head: out[g] = relu(g@fc1+b1) @ out_w + out_b ----------------
__global__ __launch_bounds__(256) void k_head(const float* __restrict__ gpool,
                                              const float* __restrict__ w1,
                                              const float* __restrict__ b1,
                                              const float* __restrict__ w2,
                                              const float* __restrict__ b2,
                                              float* __restrict__ out){
    __shared__ float red[256];
    int g = blockIdx.x, t = threadIdx.x;
    float acc = b1[t];
    const float* gp = gpool + g * 512;
    #pragma unroll 4
    for (int k = 0; k < 512; k++) acc += gp[k] * w1[k * HD + t];
    red[t] = relu_f(acc) * w2[t];
    __syncthreads();
    for (int s = 128; s > 0; s >>= 1){
        if (t < s) red[t] += red[t + s];
        __syncthreads();
    }
    if (t == 0) out[g] = red[0] + b2[0];
}

extern "C" void kernel_launch(void* const* d_in, const int* in_sizes, int n_in,
                              void* d_out, int out_size, void* d_ws, size_t ws_size,
                              hipStream_t stream){
    const float* x      = (const float*)d_in[0];
    const int*   ei     = (const int*)d_in[1];
    const int*   batch  = (const int*)d_in[2];
    const float* gcn_w[4] = {(const float*)d_in[3], (const float*)d_in[5], (const float*)d_in[7], (const float*)d_in[9]};
    const float* gcn_b[4] = {(const float*)d_in[4], (const float*)d_in[6], (const float*)d_in[8], (const float*)d_in[10]};
    const float* ec1_w1 = (const float*)d_in[11]; const float* ec1_b1 = (const float*)d_in[12];
    const float* ec1_w2 = (const float*)d_in[13]; const float* ec1_b2 = (const float*)d_in[14];
    const float* ec2_w1 = (const float*)d_in[15]; const float* ec2_b1 = (const float*)d_in[16];
    const float* ec2_w2 = (const float*)d_in[17]; const float* ec2_b2 = (const float*)d_in[18];
    const float* fc1_w  = (const float*)d_in[19]; const float* fc1_b  = (const float*)d_in[20];
    const float* out_w  = (const float*)d_in[21]; const float* out_b  = (const float*)d_in[22];

    const int N = in_sizes[2];
    const int E = in_sizes[1] / 2;
    const int F = in_sizes[0] / N;       // 128
    const int* src = ei;
    const int* dst = ei + E;

    // workspace carve-out (~88 MB)
    char* w = (char*)d_ws;
    auto alloc = [&](size_t bytes) -> char* {
        char* p = w;
        w += (bytes + 255) & ~(size_t)255;
        return p;
    };
    int*   cnt     = (int*)alloc((size_t)N * 4);
    int*   fillc   = (int*)alloc((size_t)N * 4);
    int*   row_ptr = (int*)alloc((size_t)(N + 1) * 4);
    int*   csr_src = (int*)alloc((size_t)E * 4);
    int*   csr_dst = (int*)alloc((size_t)E * 4);
    float* dinv    = (float*)alloc((size_t)N * 4);
    float* wd      = (float*)alloc((size_t)HD * HD * 4);
    float* act     = (float*)alloc((size_t)N * HD * 4);   // GCN activation (final xg lives here)
    float* hbuf    = (float*)alloc((size_t)N * HD * 4);   // GEMM out / EdgeConv A
    float* Bbuf    = (float*)alloc((size_t)N * HD * 4);   // EdgeConv B
    float* xebuf   = (float*)alloc((size_t)N * HD * 4);   // EdgeConv output (max-agg, relu'd)
    float* gpool   = (float*)alloc((size_t)64 * 512 * 4);

    // ---- CSR + deg norm ----
    hipMemsetAsync(cnt, 0, (size_t)N * 4, stream);
    hipMemsetAsync(fillc, 0, (size_t)N * 4, stream);
    k_count<<<(E + 255) / 256, 256, 0, stream>>>(dst, cnt, E);
    k_dinv<<<(N + 255) / 256, 256, 0, stream>>>(cnt, dinv, N);
    k_scan<<<1, 1024, 0, stream>>>(cnt, row_ptr, N);
    k_fill<<<(E + 255) / 256, 256, 0, stream>>>(src, dst, row_ptr, fillc, csr_src, csr_dst, E);

    // ---- GCN branch ----
    k_gemm<<<N / 32, 256, 0, stream>>>(x, gcn_w[0], nullptr, hbuf, N, F);
    k_gcn_agg<<<N / 4, 256, 0, stream>>>(hbuf, dinv, row_ptr, csr_src, gcn_b[0], act, N);
    for (int l = 1; l < 4; l++){
        k_gemm<<<N / 32, 256, 0, stream>>>(act, gcn_w[l], nullptr, hbuf, N, HD);
        k_gcn_agg<<<N / 4, 256, 0, stream>>>(hbuf, dinv, row_ptr, csr_src, gcn_b[l], act, N);
    }

    // ---- EdgeConv 1 (input x, K=F) ----
    k_wdiff<<<(F * HD + 255) / 256, 256, 0, stream>>>(ec1_w1, wd, F);
    k_gemm<<<N / 32, 256, 0, stream>>>(x, wd, ec1_b1, hbuf, N, F);               // A = x@(Wt-Wb)+b1
    k_gemm<<<N / 32, 256, 0, stream>>>(x, ec1_w1 + (size_t)F * HD, nullptr, Bbuf, N, F);  // B = x@Wb
    hipMemsetAsync(xebuf, 0, (size_t)N * HD * 4, stream);
    k_edge<<<E / 64, 256, 0, stream>>>(hbuf, Bbuf, ec1_w2, ec1_b2, csr_src, csr_dst, xebuf);

    // ---- EdgeConv 2 (input xe, K=HD) ----
    k_wdiff<<<(HD * HD + 255) / 256, 256, 0, stream>>>(ec2_w1, wd, HD);
    k_gemm<<<N / 32, 256, 0, stream>>>(xebuf, wd, ec2_b1, hbuf, N, HD);
    k_gemm<<<N / 32, 256, 0, stream>>>(xebuf, ec2_w1 + (size_t)HD * HD, nullptr, Bbuf, N, HD);
    hipMemsetAsync(xebuf, 0, (size_t)N * HD * 4, stream);
    k_edge<<<E / 64, 256, 0, stream>>>(hbuf, Bbuf, ec2_w2, ec2_b2, csr_src, csr_dst, xebuf);

    // ---- pool + head ----
    k_pool<<<64, 512, 0, stream>>>(act, xebuf, batch, gpool, N);
    k_head<<<64, 256, 0, stream>>>(gpool, fc1_w, fc1_b, out_w, out_b, (float*)d_out);
}

// Round 4
// 1953.033 us; speedup vs baseline: 1.5299x; 1.5299x over previous
//
#include <hip/hip_runtime.h>

#define HD 256   // hidden dim H

typedef __attribute__((ext_vector_type(8))) __bf16 bf16x8;
typedef __attribute__((ext_vector_type(4))) float f32x4;

static __device__ __forceinline__ float relu_f(float x){ return x > 0.f ? x : 0.f; }

// ---------------- CSR build ----------------
__global__ void k_count(const int* __restrict__ dst, int* __restrict__ cnt, int E){
    int i = blockIdx.x * blockDim.x + threadIdx.x;
    if (i < E) atomicAdd(&cnt[dst[i]], 1);
}

__global__ void k_dinv(const int* __restrict__ cnt, float* __restrict__ dinv, int n){
    int i = blockIdx.x * blockDim.x + threadIdx.x;
    if (i < n) dinv[i] = 1.0f / sqrtf((float)(cnt[i] + 1));   // +1 self loop
}

// single-block chunked Hillis-Steele exclusive scan
__global__ void k_scan(const int* __restrict__ cnt, int* __restrict__ row_ptr, int n){
    __shared__ int lds[1024];
    int t = threadIdx.x;
    int carry = 0;
    for (int base = 0; base < n; base += 1024){
        int idx = base + t;
        int v = (idx < n) ? cnt[idx] : 0;
        __syncthreads();
        lds[t] = v;
        __syncthreads();
        for (int off = 1; off < 1024; off <<= 1){
            int add = (t >= off) ? lds[t - off] : 0;
            __syncthreads();
            lds[t] += add;
            __syncthreads();
        }
        int incl = lds[t];
        if (idx < n) row_ptr[idx] = carry + incl - v;   // exclusive
        carry += lds[1023];
    }
    if (t == 0) row_ptr[n] = carry;
}

__global__ void k_fill(const int* __restrict__ src, const int* __restrict__ dst,
                       const int* __restrict__ row_ptr, int* __restrict__ fill,
                       int* __restrict__ csr_src, int* __restrict__ csr_dst, int E){
    int i = blockIdx.x * blockDim.x + threadIdx.x;
    if (i < E){
        int d = dst[i];
        int pos = row_ptr[d] + atomicAdd(&fill[d], 1);
        csr_src[pos] = src[i];
        csr_dst[pos] = d;
    }
}

// ---------------- dense node GEMM: C[M,256] = A[M,K] @ W[K,256] (+bias) ----------------
__global__ __launch_bounds__(256) void k_gemm(const float* __restrict__ A,
                                              const float* __restrict__ W,
                                              const float* __restrict__ bias,
                                              float* __restrict__ C, int M, int K){
    __shared__ float As[16][36];
    __shared__ float Ws[16][HD];
    int t = threadIdx.x;
    int m0 = blockIdx.x * 32;
    int tr = t >> 5, tc = t & 31;
    int srow = t >> 3, skk = (t & 7) * 2;
    int wkr = t >> 4, wc0 = (t & 15) * 16;

    float acc[4][8];
    #pragma unroll
    for (int i = 0; i < 4; i++)
        #pragma unroll
        for (int j = 0; j < 8; j++) acc[i][j] = 0.f;

    const float* Arow = A + (size_t)(m0 + srow) * K + skk;

    for (int k0 = 0; k0 < K; k0 += 16){
        float2 av = *(const float2*)(Arow + k0);
        As[skk][srow] = av.x;
        As[skk + 1][srow] = av.y;
        const float* wp = W + (size_t)(k0 + wkr) * HD + wc0;
        #pragma unroll
        for (int j = 0; j < 4; j++)
            *(float4*)&Ws[wkr][wc0 + 4 * j] = *(const float4*)(wp + 4 * j);
        __syncthreads();
        #pragma unroll
        for (int k = 0; k < 16; k++){
            float4 m4 = *(const float4*)&As[k][tr * 4];
            float4 wa = *(const float4*)&Ws[k][tc * 8];
            float4 wb = *(const float4*)&Ws[k][tc * 8 + 4];
            float mm[4] = {m4.x, m4.y, m4.z, m4.w};
            float ww[8] = {wa.x, wa.y, wa.z, wa.w, wb.x, wb.y, wb.z, wb.w};
            #pragma unroll
            for (int i = 0; i < 4; i++)
                #pragma unroll
                for (int j = 0; j < 8; j++) acc[i][j] += mm[i] * ww[j];
        }
        __syncthreads();
    }

    float bj[8];
    #pragma unroll
    for (int j = 0; j < 8; j++) bj[j] = bias ? bias[tc * 8 + j] : 0.f;
    #pragma unroll
    for (int i = 0; i < 4; i++){
        float* cp = C + (size_t)(m0 + tr * 4 + i) * HD + tc * 8;
        float4 o0 = {acc[i][0] + bj[0], acc[i][1] + bj[1], acc[i][2] + bj[2], acc[i][3] + bj[3]};
        float4 o1 = {acc[i][4] + bj[4], acc[i][5] + bj[5], acc[i][6] + bj[6], acc[i][7] + bj[7]};
        *(float4*)cp = o0;
        *(float4*)(cp + 4) = o1;
    }
}

// ---------------- GCN aggregate ----------------
__global__ __launch_bounds__(256) void k_gcn_agg(const float* __restrict__ h,
                                                 const float* __restrict__ dinv,
                                                 const int* __restrict__ row_ptr,
                                                 const int* __restrict__ csr_src,
                                                 const float* __restrict__ bias,
                                                 float* __restrict__ out, int n){
    int wid = threadIdx.x >> 6, lane = threadIdx.x & 63;
    int i = blockIdx.x * 4 + wid;
    if (i >= n) return;
    float di = dinv[i];
    const float4* hp = (const float4*)h;
    float4 v = hp[(size_t)i * 64 + lane];
    float ax = v.x * di, ay = v.y * di, az = v.z * di, aw = v.w * di;
    int e0 = row_ptr[i], e1 = row_ptr[i + 1];
    for (int e = e0; e < e1; e++){
        int s = csr_src[e];
        float ds = dinv[s];
        float4 u = hp[(size_t)s * 64 + lane];
        ax += u.x * ds; ay += u.y * ds; az += u.z * ds; aw += u.w * ds;
    }
    const float4 b = ((const float4*)bias)[lane];
    float4 o;
    o.x = relu_f(ax * di + b.x);
    o.y = relu_f(ay * di + b.y);
    o.z = relu_f(az * di + b.z);
    o.w = relu_f(aw * di + b.w);
    ((float4*)out)[(size_t)i * 64 + lane] = o;
}

// ---------------- W2 pack: fragment-ordered bf16 hi/lo ----------------
// Wp[((ks*256 + c)*4 + g)*8 + j] = W[ks*32 + g*8 + j][c]  (ks:8, c:256, g:4, j:8)
__global__ void k_wpack(const float* __restrict__ W, __bf16* __restrict__ ph, __bf16* __restrict__ pl){
    int idx = blockIdx.x * blockDim.x + threadIdx.x;
    if (idx >= 8 * 256 * 4 * 8) return;
    int j = idx & 7, g = (idx >> 3) & 3, c = (idx >> 5) & 255, ks = idx >> 13;
    int k = ks * 32 + g * 8 + j;
    float v = W[(size_t)k * HD + c];
    __bf16 h = (__bf16)v;
    ph[idx] = h;
    pl[idx] = (__bf16)(v - (float)h);
}

// ---------------- fused EdgeConv: MFMA edge GEMM + max-aggregate ----------------
// Block: 64 CSR-ordered edges x 256 outputs, K=256. 4 waves; wave w owns cols [64w,64w+64).
// msg = relu(A[dst]+B[src]) split to bf16 hi/lo in LDS per 32-k chunk; 3 MFMAs/product
// (mh*wh + ml*wh + mh*wl) for ~fp32 precision. Epilogue: dst-run max + atomicMax (out init 0).
__global__ __launch_bounds__(256) void k_edge_mfma(
    const float* __restrict__ A, const float* __restrict__ B,
    const __bf16* __restrict__ Wph, const __bf16* __restrict__ Wpl,
    const float* __restrict__ bias,
    const int* __restrict__ csr_src, const int* __restrict__ csr_dst,
    float* __restrict__ out, int E)
{
    __shared__ __bf16 mh[64][40];   // row stride 80B -> max 2-way bank aliasing (free)
    __shared__ __bf16 ml[64][40];
    __shared__ int sdst[64], ssrc[64];
    int t = threadIdx.x;
    int p0 = blockIdx.x * 64;
    if (t < 64){
        int e = p0 + t; if (e >= E) e = E - 1;   // duplicate edge: idempotent under max
        sdst[t] = csr_dst[e];
        ssrc[t] = csr_src[e];
    }
    __syncthreads();

    const int w  = t >> 6;           // wave id
    const int fr = t & 15;           // lane & 15
    const int fg = (t & 63) >> 4;    // lane >> 4
    const int srow = t >> 2, skb = (t & 3) * 8;   // staging row / k-base
    const float* Arow = A + (size_t)sdst[srow] * HD + skb;
    const float* Brow = B + (size_t)ssrc[srow] * HD + skb;
    const int c0 = w * 64 + fr;

    f32x4 acc[4][4];
    #pragma unroll
    for (int i = 0; i < 4; i++)
        #pragma unroll
        for (int j = 0; j < 4; j++) acc[i][j] = (f32x4){0.f, 0.f, 0.f, 0.f};

    for (int ks = 0; ks < 8; ++ks){
        // gather + message build (fp32), hi/lo split
        float4 a0 = *(const float4*)(Arow + ks * 32);
        float4 a1 = *(const float4*)(Arow + ks * 32 + 4);
        float4 g0 = *(const float4*)(Brow + ks * 32);
        float4 g1 = *(const float4*)(Brow + ks * 32 + 4);
        float m8[8] = {a0.x + g0.x, a0.y + g0.y, a0.z + g0.z, a0.w + g0.w,
                       a1.x + g1.x, a1.y + g1.y, a1.z + g1.z, a1.w + g1.w};
        bf16x8 vh, vl;
        #pragma unroll
        for (int j = 0; j < 8; j++){
            float m = relu_f(m8[j]);
            __bf16 h = (__bf16)m;
            vh[j] = h;
            vl[j] = (__bf16)(m - (float)h);
        }
        // B-fragments from packed W2 (global, L2-resident), independent of LDS
        bf16x8 bh[4], bl[4];
        #pragma unroll
        for (int nf = 0; nf < 4; nf++){
            size_t bi = ((size_t)(ks * 256 + c0 + nf * 16) * 4 + fg) * 8;
            bh[nf] = *(const bf16x8*)(Wph + bi);
            bl[nf] = *(const bf16x8*)(Wpl + bi);
        }
        __syncthreads();   // previous chunk's LDS reads done
        *(bf16x8*)&mh[srow][skb] = vh;
        *(bf16x8*)&ml[srow][skb] = vl;
        __syncthreads();   // staging visible
        #pragma unroll
        for (int mf = 0; mf < 4; mf++){
            bf16x8 ah = *(const bf16x8*)&mh[mf * 16 + fr][fg * 8];
            bf16x8 al = *(const bf16x8*)&ml[mf * 16 + fr][fg * 8];
            #pragma unroll
            for (int nf = 0; nf < 4; nf++){
                acc[mf][nf] = __builtin_amdgcn_mfma_f32_16x16x32_bf16(ah, bh[nf], acc[mf][nf], 0, 0, 0);
                acc[mf][nf] = __builtin_amdgcn_mfma_f32_16x16x32_bf16(al, bh[nf], acc[mf][nf], 0, 0, 0);
                acc[mf][nf] = __builtin_amdgcn_mfma_f32_16x16x32_bf16(ah, bl[nf], acc[mf][nf], 0, 0, 0);
            }
        }
    }

    // epilogue: C/D layout col = lane&15 (-> c0+nf*16), row = fg*4 + reg (-> edge row)
    float bj[4];
    #pragma unroll
    for (int nf = 0; nf < 4; nf++) bj[nf] = bias[c0 + nf * 16];
    #pragma unroll
    for (int mf = 0; mf < 4; mf++){
        int r0 = mf * 16 + fg * 4;
        int curd = sdst[r0];
        float v[4];
        #pragma unroll
        for (int nf = 0; nf < 4; nf++) v[nf] = acc[mf][nf][0] + bj[nf];
        #pragma unroll
        for (int reg = 1; reg < 4; reg++){
            int d = sdst[r0 + reg];
            if (d != curd){
                #pragma unroll
                for (int nf = 0; nf < 4; nf++)
                    if (v[nf] > 0.f)
                        atomicMax((int*)(out + (size_t)curd * HD + c0 + nf * 16), __float_as_int(v[nf]));
                curd = d;
                #pragma unroll
                for (int nf = 0; nf < 4; nf++) v[nf] = acc[mf][nf][reg] + bj[nf];
            } else {
                #pragma unroll
                for (int nf = 0; nf < 4; nf++) v[nf] = fmaxf(v[nf], acc[mf][nf][reg] + bj[nf]);
            }
        }
        #pragma unroll
        for (int nf = 0; nf < 4; nf++)
            if (v[nf] > 0.f)
                atomicMax((int*)(out + (size_t)curd * HD + c0 + nf * 16), __float_as_int(v[nf]));
    }
}

// ---------------- Wd = W_top - W_bot ----------------
__global__ void k_wdiff(const float* __restrict__ w, float* __restrict__ wd, int K){
    int i = blockIdx.x * blockDim.x + threadIdx.x;
    if (i < K * HD) wd[i] = w[i] - w[K * HD + i];
}

// ---------------- per-graph sum pool ----------------
__global__ __launch_bounds__(512) void k_pool(const float* __restrict__ xg,
                                              const float* __restrict__ xe,
                                              const int* __restrict__ batch,
                                              float* __restrict__ gpool, int n){
    int g = blockIdx.x, t = threadIdx.x;
    int lo, hi;
    { int l = 0, h = n; while (l < h){ int m = (l + h) >> 1; if (batch[m] < g) l = m + 1; else h = m; } lo = l; }
    { int l = lo, h = n; while (l < h){ int m = (l + h) >> 1; if (batch[m] < g + 1) l = m + 1; else h = m; } hi = l; }
    const float* sp = (t < 256) ? (xg + t) : (xe + (t - 256));
    float a0 = 0.f, a1 = 0.f;
    int i = lo;
    for (; i + 1 < hi; i += 2){
        a0 += sp[(size_t)i * HD];
        a1 += sp[(size_t)(i + 1) * HD];
    }
    if (i < hi) a0 += sp[(size_t)i * HD];
    gpool[g * 512 + t] = a0 + a1;
}

// ---------------- head ----------------
__global__ __launch_bounds__(256) void k_head(const float* __restrict__ gpool,
                                              const float* __restrict__ w1,
                                              const float* __restrict__ b1,
                                              const float* __restrict__ w2,
                                              const float* __restrict__ b2,
                                              float* __restrict__ out){
    __shared__ float red[256];
    int g = blockIdx.x, t = threadIdx.x;
    float acc = b1[t];
    const float* gp = gpool + g * 512;
    #pragma unroll 4
    for (int k = 0; k < 512; k++) acc += gp[k] * w1[k * HD + t];
    red[t] = relu_f(acc) * w2[t];
    __syncthreads();
    for (int s = 128; s > 0; s >>= 1){
        if (t < s) red[t] += red[t + s];
        __syncthreads();
    }
    if (t == 0) out[g] = red[0] + b2[0];
}

extern "C" void kernel_launch(void* const* d_in, const int* in_sizes, int n_in,
                              void* d_out, int out_size, void* d_ws, size_t ws_size,
                              hipStream_t stream){
    const float* x      = (const float*)d_in[0];
    const int*   ei     = (const int*)d_in[1];
    const int*   batch  = (const int*)d_in[2];
    const float* gcn_w[4] = {(const float*)d_in[3], (const float*)d_in[5], (const float*)d_in[7], (const float*)d_in[9]};
    const float* gcn_b[4] = {(const float*)d_in[4], (const float*)d_in[6], (const float*)d_in[8], (const float*)d_in[10]};
    const float* ec1_w1 = (const float*)d_in[11]; const float* ec1_b1 = (const float*)d_in[12];
    const float* ec1_w2 = (const float*)d_in[13]; const float* ec1_b2 = (const float*)d_in[14];
    const float* ec2_w1 = (const float*)d_in[15]; const float* ec2_b1 = (const float*)d_in[16];
    const float* ec2_w2 = (const float*)d_in[17]; const float* ec2_b2 = (const float*)d_in[18];
    const float* fc1_w  = (const float*)d_in[19]; const float* fc1_b  = (const float*)d_in[20];
    const float* out_w  = (const float*)d_in[21]; const float* out_b  = (const float*)d_in[22];

    const int N = in_sizes[2];
    const int E = in_sizes[1] / 2;
    const int F = in_sizes[0] / N;       // 128
    const int* src = ei;
    const int* dst = ei + E;

    char* w = (char*)d_ws;
    auto alloc = [&](size_t bytes) -> char* {
        char* p = w;
        w += (bytes + 255) & ~(size_t)255;
        return p;
    };
    int*   cnt     = (int*)alloc((size_t)N * 4);
    int*   fillc   = (int*)alloc((size_t)N * 4);
    int*   row_ptr = (int*)alloc((size_t)(N + 1) * 4);
    int*   csr_src = (int*)alloc((size_t)E * 4);
    int*   csr_dst = (int*)alloc((size_t)E * 4);
    float* dinv    = (float*)alloc((size_t)N * 4);
    float* wd      = (float*)alloc((size_t)HD * HD * 4);
    float* act     = (float*)alloc((size_t)N * HD * 4);
    float* hbuf    = (float*)alloc((size_t)N * HD * 4);
    float* Bbuf    = (float*)alloc((size_t)N * HD * 4);
    float* xebuf   = (float*)alloc((size_t)N * HD * 4);
    float* gpool   = (float*)alloc((size_t)64 * 512 * 4);
    __bf16* w2h1   = (__bf16*)alloc((size_t)65536 * 2);
    __bf16* w2l1   = (__bf16*)alloc((size_t)65536 * 2);
    __bf16* w2h2   = (__bf16*)alloc((size_t)65536 * 2);
    __bf16* w2l2   = (__bf16*)alloc((size_t)65536 * 2);

    // ---- CSR + deg norm + weight packs ----
    hipMemsetAsync(cnt, 0, (size_t)N * 4, stream);
    hipMemsetAsync(fillc, 0, (size_t)N * 4, stream);
    k_count<<<(E + 255) / 256, 256, 0, stream>>>(dst, cnt, E);
    k_dinv<<<(N + 255) / 256, 256, 0, stream>>>(cnt, dinv, N);
    k_scan<<<1, 1024, 0, stream>>>(cnt, row_ptr, N);
    k_fill<<<(E + 255) / 256, 256, 0, stream>>>(src, dst, row_ptr, fillc, csr_src, csr_dst, E);
    k_wpack<<<256, 256, 0, stream>>>(ec1_w2, w2h1, w2l1);
    k_wpack<<<256, 256, 0, stream>>>(ec2_w2, w2h2, w2l2);

    // ---- GCN branch ----
    k_gemm<<<N / 32, 256, 0, stream>>>(x, gcn_w[0], nullptr, hbuf, N, F);
    k_gcn_agg<<<N / 4, 256, 0, stream>>>(hbuf, dinv, row_ptr, csr_src, gcn_b[0], act, N);
    for (int l = 1; l < 4; l++){
        k_gemm<<<N / 32, 256, 0, stream>>>(act, gcn_w[l], nullptr, hbuf, N, HD);
        k_gcn_agg<<<N / 4, 256, 0, stream>>>(hbuf, dinv, row_ptr, csr_src, gcn_b[l], act, N);
    }

    // ---- EdgeConv 1 ----
    k_wdiff<<<(F * HD + 255) / 256, 256, 0, stream>>>(ec1_w1, wd, F);
    k_gemm<<<N / 32, 256, 0, stream>>>(x, wd, ec1_b1, hbuf, N, F);
    k_gemm<<<N / 32, 256, 0, stream>>>(x, ec1_w1 + (size_t)F * HD, nullptr, Bbuf, N, F);
    hipMemsetAsync(xebuf, 0, (size_t)N * HD * 4, stream);
    k_edge_mfma<<<E / 64, 256, 0, stream>>>(hbuf, Bbuf, w2h1, w2l1, ec1_b2, csr_src, csr_dst, xebuf, E);

    // ---- EdgeConv 2 ----
    k_wdiff<<<(HD * HD + 255) / 256, 256, 0, stream>>>(ec2_w1, wd, HD);
    k_gemm<<<N / 32, 256, 0, stream>>>(xebuf, wd, ec2_b1, hbuf, N, HD);
    k_gemm<<<N / 32, 256, 0, stream>>>(xebuf, ec2_w1 + (size_t)HD * HD, nullptr, Bbuf, N, HD);
    hipMemsetAsync(xebuf, 0, (size_t)N * HD * 4, stream);
    k_edge_mfma<<<E / 64, 256, 0, stream>>>(hbuf, Bbuf, w2h2, w2l2, ec2_b2, csr_src, csr_dst, xebuf, E);

    // ---- pool + head ----
    k_pool<<<64, 512, 0, stream>>>(act, xebuf, batch, gpool, N);
    k_head<<<64, 256, 0, stream>>>(gpool, fc1_w, fc1_b, out_w, out_b, (float*)d_out);
}

// Round 5
// 1444.544 us; speedup vs baseline: 2.0685x; 1.3520x over previous
//
#include <hip/hip_runtime.h>

#define HD 256   // hidden dim H

typedef __attribute__((ext_vector_type(8))) __bf16 bf16x8;
typedef __attribute__((ext_vector_type(4))) float f32x4;

static __device__ __forceinline__ float relu_f(float x){ return x > 0.f ? x : 0.f; }

// split fp32x8 -> bf16 hi/lo
static __device__ __forceinline__ void split_cvt(const float* m8, bf16x8& vh, bf16x8& vl){
    #pragma unroll
    for (int j = 0; j < 8; j++){
        float m = m8[j];
        __bf16 h = (__bf16)m;
        vh[j] = h;
        vl[j] = (__bf16)(m - (float)h);
    }
}

// ---------------- CSR build ----------------
__global__ void k_count(const int* __restrict__ dst, int* __restrict__ cnt, int E){
    int i = blockIdx.x * blockDim.x + threadIdx.x;
    if (i < E) atomicAdd(&cnt[dst[i]], 1);
}

__global__ void k_dinv(const int* __restrict__ cnt, float* __restrict__ dinv, int n){
    int i = blockIdx.x * blockDim.x + threadIdx.x;
    if (i < n) dinv[i] = 1.0f / sqrtf((float)(cnt[i] + 1));   // +1 self loop
}

// single-block chunked Hillis-Steele exclusive scan
__global__ void k_scan(const int* __restrict__ cnt, int* __restrict__ row_ptr, int n){
    __shared__ int lds[1024];
    int t = threadIdx.x;
    int carry = 0;
    for (int base = 0; base < n; base += 1024){
        int idx = base + t;
        int v = (idx < n) ? cnt[idx] : 0;
        __syncthreads();
        lds[t] = v;
        __syncthreads();
        for (int off = 1; off < 1024; off <<= 1){
            int add = (t >= off) ? lds[t - off] : 0;
            __syncthreads();
            lds[t] += add;
            __syncthreads();
        }
        int incl = lds[t];
        if (idx < n) row_ptr[idx] = carry + incl - v;   // exclusive
        carry += lds[1023];
    }
    if (t == 0) row_ptr[n] = carry;
}

__global__ void k_fill(const int* __restrict__ src, const int* __restrict__ dst,
                       const int* __restrict__ row_ptr, int* __restrict__ fill,
                       int* __restrict__ csr_src, int* __restrict__ csr_dst, int E){
    int i = blockIdx.x * blockDim.x + threadIdx.x;
    if (i < E){
        int d = dst[i];
        int pos = row_ptr[d] + atomicAdd(&fill[d], 1);
        csr_src[pos] = src[i];
        csr_dst[pos] = d;
    }
}

// ---------------- W pack: fragment-ordered bf16 hi/lo (any K multiple of 32) ----------------
// Wp[((ks*256 + c)*4 + g)*8 + j] = W[ks*32 + g*8 + j][c]
__global__ void k_wpack(const float* __restrict__ W, __bf16* __restrict__ ph,
                        __bf16* __restrict__ pl, int K){
    int total = (K >> 5) * 8192;
    int idx = blockIdx.x * blockDim.x + threadIdx.x;
    if (idx >= total) return;
    int j = idx & 7, g = (idx >> 3) & 3, c = (idx >> 5) & 255, ks = idx >> 13;
    int k = ks * 32 + g * 8 + j;
    float v = W[(size_t)k * HD + c];
    __bf16 h = (__bf16)v;
    ph[idx] = h;
    pl[idx] = (__bf16)(v - (float)h);
}

// ---------------- Wd = W_top - W_bot ----------------
__global__ void k_wdiff(const float* __restrict__ w, float* __restrict__ wd, int K){
    int i = blockIdx.x * blockDim.x + threadIdx.x;
    if (i < K * HD) wd[i] = w[i] - w[K * HD + i];
}

// ---------------- MFMA node GEMM: C[M,256] = A[M,K] @ W (+bias), hi/lo bf16 3-MFMA ----------------
// Block: 64 rows x 256 cols, 4 waves (wave w -> cols [64w,64w+64)). Double-buffered LDS staging.
__global__ __launch_bounds__(256) void k_gemm_mfma(
    const float* __restrict__ A,
    const __bf16* __restrict__ Wph, const __bf16* __restrict__ Wpl,
    const float* __restrict__ bias,
    float* __restrict__ C, int M, int K)
{
    __shared__ __bf16 mh[2][64][40];   // row stride 80B
    __shared__ __bf16 ml[2][64][40];
    int t = threadIdx.x;
    int m0 = blockIdx.x * 64;
    const int w = t >> 6, fr = t & 15, fg = (t & 63) >> 4;
    const int srow = t >> 2, skb = (t & 3) * 8;
    int ar = m0 + srow; if (ar >= M) ar = M - 1;     // clamp loads; stores guarded
    const float* Arow = A + (size_t)ar * K + skb;
    const int c0 = w * 64 + fr;
    const int KS = K >> 5;

    f32x4 acc[4][4];
    #pragma unroll
    for (int i = 0; i < 4; i++)
        #pragma unroll
        for (int j = 0; j < 4; j++) acc[i][j] = (f32x4){0.f, 0.f, 0.f, 0.f};

    {
        float4 a0 = *(const float4*)(Arow);
        float4 a1 = *(const float4*)(Arow + 4);
        float m8[8] = {a0.x, a0.y, a0.z, a0.w, a1.x, a1.y, a1.z, a1.w};
        bf16x8 vh, vl;
        split_cvt(m8, vh, vl);
        *(bf16x8*)&mh[0][srow][skb] = vh;
        *(bf16x8*)&ml[0][srow][skb] = vl;
    }

    for (int ks = 0; ks < KS; ++ks){
        float4 a0, a1;
        if (ks + 1 < KS){
            a0 = *(const float4*)(Arow + (ks + 1) * 32);
            a1 = *(const float4*)(Arow + (ks + 1) * 32 + 4);
        }
        bf16x8 bh[4], bl[4];
        #pragma unroll
        for (int nf = 0; nf < 4; nf++){
            size_t bi = ((size_t)(ks * 256 + c0 + nf * 16) * 4 + fg) * 8;
            bh[nf] = *(const bf16x8*)(Wph + bi);
            bl[nf] = *(const bf16x8*)(Wpl + bi);
        }
        __syncthreads();             // buf[ks&1] staged; prev readers of buf[ks+1&1] done
        const int cb = ks & 1;
        #pragma unroll
        for (int mf = 0; mf < 4; mf++){
            bf16x8 ah = *(const bf16x8*)&mh[cb][mf * 16 + fr][fg * 8];
            bf16x8 al = *(const bf16x8*)&ml[cb][mf * 16 + fr][fg * 8];
            #pragma unroll
            for (int nf = 0; nf < 4; nf++){
                acc[mf][nf] = __builtin_amdgcn_mfma_f32_16x16x32_bf16(ah, bh[nf], acc[mf][nf], 0, 0, 0);
                acc[mf][nf] = __builtin_amdgcn_mfma_f32_16x16x32_bf16(al, bh[nf], acc[mf][nf], 0, 0, 0);
                acc[mf][nf] = __builtin_amdgcn_mfma_f32_16x16x32_bf16(ah, bl[nf], acc[mf][nf], 0, 0, 0);
            }
        }
        if (ks + 1 < KS){
            float m8[8] = {a0.x, a0.y, a0.z, a0.w, a1.x, a1.y, a1.z, a1.w};
            bf16x8 vh, vl;
            split_cvt(m8, vh, vl);
            *(bf16x8*)&mh[cb ^ 1][srow][skb] = vh;
            *(bf16x8*)&ml[cb ^ 1][srow][skb] = vl;
        }
    }

    float bj[4];
    #pragma unroll
    for (int nf = 0; nf < 4; nf++) bj[nf] = bias ? bias[c0 + nf * 16] : 0.f;
    #pragma unroll
    for (int mf = 0; mf < 4; mf++)
        #pragma unroll
        for (int reg = 0; reg < 4; reg++){
            int row = m0 + mf * 16 + fg * 4 + reg;   // C/D: col=lane&15, row=fg*4+reg (verified)
            if (row < M){
                #pragma unroll
                for (int nf = 0; nf < 4; nf++)
                    C[(size_t)row * HD + c0 + nf * 16] = acc[mf][nf][reg] + bj[nf];
            }
        }
}

// ---------------- GCN aggregate ----------------
__global__ __launch_bounds__(256) void k_gcn_agg(const float* __restrict__ h,
                                                 const float* __restrict__ dinv,
                                                 const int* __restrict__ row_ptr,
                                                 const int* __restrict__ csr_src,
                                                 const float* __restrict__ bias,
                                                 float* __restrict__ out, int n){
    int wid = threadIdx.x >> 6, lane = threadIdx.x & 63;
    int i = blockIdx.x * 4 + wid;
    if (i >= n) return;
    float di = dinv[i];
    const float4* hp = (const float4*)h;
    float4 v = hp[(size_t)i * 64 + lane];
    float ax = v.x * di, ay = v.y * di, az = v.z * di, aw = v.w * di;
    int e0 = row_ptr[i], e1 = row_ptr[i + 1];
    for (int e = e0; e < e1; e++){
        int s = csr_src[e];
        float ds = dinv[s];
        float4 u = hp[(size_t)s * 64 + lane];
        ax += u.x * ds; ay += u.y * ds; az += u.z * ds; aw += u.w * ds;
    }
    const float4 b = ((const float4*)bias)[lane];
    float4 o;
    o.x = relu_f(ax * di + b.x);
    o.y = relu_f(ay * di + b.y);
    o.z = relu_f(az * di + b.z);
    o.w = relu_f(aw * di + b.w);
    ((float4*)out)[(size_t)i * 64 + lane] = o;
}

// ---------------- fused EdgeConv: MFMA edge GEMM + max-aggregate (v2) ----------------
// Double-buffered staging (1 barrier/k-chunk), consolidated run-tracking epilogue.
__global__ __launch_bounds__(256) void k_edge_mfma(
    const float* __restrict__ A, const float* __restrict__ B,
    const __bf16* __restrict__ Wph, const __bf16* __restrict__ Wpl,
    const float* __restrict__ bias,
    const int* __restrict__ csr_src, const int* __restrict__ csr_dst,
    float* __restrict__ out, int E)
{
    __shared__ __bf16 mh[2][64][40];
    __shared__ __bf16 ml[2][64][40];
    __shared__ int sdst[64], ssrc[64];
    int t = threadIdx.x;
    int p0 = blockIdx.x * 64;
    if (t < 64){
        int e = p0 + t; if (e >= E) e = E - 1;   // duplicate edge: idempotent under max
        sdst[t] = csr_dst[e];
        ssrc[t] = csr_src[e];
    }
    __syncthreads();

    const int w  = t >> 6;
    const int fr = t & 15;
    const int fg = (t & 63) >> 4;
    const int srow = t >> 2, skb = (t & 3) * 8;
    const float* Arow = A + (size_t)sdst[srow] * HD + skb;
    const float* Brow = B + (size_t)ssrc[srow] * HD + skb;
    const int c0 = w * 64 + fr;

    f32x4 acc[4][4];
    #pragma unroll
    for (int i = 0; i < 4; i++)
        #pragma unroll
        for (int j = 0; j < 4; j++) acc[i][j] = (f32x4){0.f, 0.f, 0.f, 0.f};

    {
        float4 a0 = *(const float4*)(Arow);
        float4 a1 = *(const float4*)(Arow + 4);
        float4 g0 = *(const float4*)(Brow);
        float4 g1 = *(const float4*)(Brow + 4);
        float m8[8] = {relu_f(a0.x + g0.x), relu_f(a0.y + g0.y), relu_f(a0.z + g0.z), relu_f(a0.w + g0.w),
                       relu_f(a1.x + g1.x), relu_f(a1.y + g1.y), relu_f(a1.z + g1.z), relu_f(a1.w + g1.w)};
        bf16x8 vh, vl;
        split_cvt(m8, vh, vl);
        *(bf16x8*)&mh[0][srow][skb] = vh;
        *(bf16x8*)&ml[0][srow][skb] = vl;
    }

    for (int ks = 0; ks < 8; ++ks){
        float4 a0, a1, g0, g1;
        if (ks < 7){                                  // issue next gather early
            a0 = *(const float4*)(Arow + (ks + 1) * 32);
            a1 = *(const float4*)(Arow + (ks + 1) * 32 + 4);
            g0 = *(const float4*)(Brow + (ks + 1) * 32);
            g1 = *(const float4*)(Brow + (ks + 1) * 32 + 4);
        }
        bf16x8 bh[4], bl[4];
        #pragma unroll
        for (int nf = 0; nf < 4; nf++){
            size_t bi = ((size_t)(ks * 256 + c0 + nf * 16) * 4 + fg) * 8;
            bh[nf] = *(const bf16x8*)(Wph + bi);
            bl[nf] = *(const bf16x8*)(Wpl + bi);
        }
        __syncthreads();             // buf[ks&1] staged; prev readers of buf[(ks+1)&1] done
        const int cb = ks & 1;
        #pragma unroll
        for (int mf = 0; mf < 4; mf++){
            bf16x8 ah = *(const bf16x8*)&mh[cb][mf * 16 + fr][fg * 8];
            bf16x8 al = *(const bf16x8*)&ml[cb][mf * 16 + fr][fg * 8];
            #pragma unroll
            for (int nf = 0; nf < 4; nf++){
                acc[mf][nf] = __builtin_amdgcn_mfma_f32_16x16x32_bf16(ah, bh[nf], acc[mf][nf], 0, 0, 0);
                acc[mf][nf] = __builtin_amdgcn_mfma_f32_16x16x32_bf16(al, bh[nf], acc[mf][nf], 0, 0, 0);
                acc[mf][nf] = __builtin_amdgcn_mfma_f32_16x16x32_bf16(ah, bl[nf], acc[mf][nf], 0, 0, 0);
            }
        }
        if (ks < 7){
            float m8[8] = {relu_f(a0.x + g0.x), relu_f(a0.y + g0.y), relu_f(a0.z + g0.z), relu_f(a0.w + g0.w),
                           relu_f(a1.x + g1.x), relu_f(a1.y + g1.y), relu_f(a1.z + g1.z), relu_f(a1.w + g1.w)};
            bf16x8 vh, vl;
            split_cvt(m8, vh, vl);
            *(bf16x8*)&mh[cb ^ 1][srow][skb] = vh;
            *(bf16x8*)&ml[cb ^ 1][srow][skb] = vl;
        }
    }

    // consolidated epilogue: single run-tracking scan over this thread's 16 rows
    // (rows mf*16 + fg*4 + reg are ascending in mf,reg; sdst non-decreasing in CSR order)
    float bj[4];
    #pragma unroll
    for (int nf = 0; nf < 4; nf++) bj[nf] = bias[c0 + nf * 16];
    int curd = sdst[fg * 4];
    float v[4];
    #pragma unroll
    for (int nf = 0; nf < 4; nf++) v[nf] = acc[0][nf][0] + bj[nf];
    #pragma unroll
    for (int mf = 0; mf < 4; mf++){
        #pragma unroll
        for (int reg = 0; reg < 4; reg++){
            if (mf == 0 && reg == 0) continue;
            int d = sdst[mf * 16 + fg * 4 + reg];
            if (d != curd){
                #pragma unroll
                for (int nf = 0; nf < 4; nf++)
                    if (v[nf] > 0.f)
                        atomicMax((int*)(out + (size_t)curd * HD + c0 + nf * 16), __float_as_int(v[nf]));
                curd = d;
                #pragma unroll
                for (int nf = 0; nf < 4; nf++) v[nf] = acc[mf][nf][reg] + bj[nf];
            } else {
                #pragma unroll
                for (int nf = 0; nf < 4; nf++) v[nf] = fmaxf(v[nf], acc[mf][nf][reg] + bj[nf]);
            }
        }
    }
    #pragma unroll
    for (int nf = 0; nf < 4; nf++)
        if (v[nf] > 0.f)
            atomicMax((int*)(out + (size_t)curd * HD + c0 + nf * 16), __float_as_int(v[nf]));
}

// ---------------- per-graph sum pool ----------------
__global__ __launch_bounds__(512) void k_pool(const float* __restrict__ xg,
                                              const float* __restrict__ xe,
                                              const int* __restrict__ batch,
                                              float* __restrict__ gpool, int n){
    int g = blockIdx.x, t = threadIdx.x;
    int lo, hi;
    { int l = 0, h = n; while (l < h){ int m = (l + h) >> 1; if (batch[m] < g) l = m + 1; else h = m; } lo = l; }
    { int l = lo, h = n; while (l < h){ int m = (l + h) >> 1; if (batch[m] < g + 1) l = m + 1; else h = m; } hi = l; }
    const float* sp = (t < 256) ? (xg + t) : (xe + (t - 256));
    float a0 = 0.f, a1 = 0.f;
    int i = lo;
    for (; i + 1 < hi; i += 2){
        a0 += sp[(size_t)i * HD];
        a1 += sp[(size_t)(i + 1) * HD];
    }
    if (i < hi) a0 += sp[(size_t)i * HD];
    gpool[g * 512 + t] = a0 + a1;
}

// ---------------- head ----------------
__global__ __launch_bounds__(256) void k_head(const float* __restrict__ gpool,
                                              const float* __restrict__ w1,
                                              const float* __restrict__ b1,
                                              const float* __restrict__ w2,
                                              const float* __restrict__ b2,
                                              float* __restrict__ out){
    __shared__ float red[256];
    int g = blockIdx.x, t = threadIdx.x;
    float acc = b1[t];
    const float* gp = gpool + g * 512;
    #pragma unroll 4
    for (int k = 0; k < 512; k++) acc += gp[k] * w1[k * HD + t];
    red[t] = relu_f(acc) * w2[t];
    __syncthreads();
    for (int s = 128; s > 0; s >>= 1){
        if (t < s) red[t] += red[t + s];
        __syncthreads();
    }
    if (t == 0) out[g] = red[0] + b2[0];
}

extern "C" void kernel_launch(void* const* d_in, const int* in_sizes, int n_in,
                              void* d_out, int out_size, void* d_ws, size_t ws_size,
                              hipStream_t stream){
    const float* x      = (const float*)d_in[0];
    const int*   ei     = (const int*)d_in[1];
    const int*   batch  = (const int*)d_in[2];
    const float* gcn_w[4] = {(const float*)d_in[3], (const float*)d_in[5], (const float*)d_in[7], (const float*)d_in[9]};
    const float* gcn_b[4] = {(const float*)d_in[4], (const float*)d_in[6], (const float*)d_in[8], (const float*)d_in[10]};
    const float* ec1_w1 = (const float*)d_in[11]; const float* ec1_b1 = (const float*)d_in[12];
    const float* ec1_w2 = (const float*)d_in[13]; const float* ec1_b2 = (const float*)d_in[14];
    const float* ec2_w1 = (const float*)d_in[15]; const float* ec2_b1 = (const float*)d_in[16];
    const float* ec2_w2 = (const float*)d_in[17]; const float* ec2_b2 = (const float*)d_in[18];
    const float* fc1_w  = (const float*)d_in[19]; const float* fc1_b  = (const float*)d_in[20];
    const float* out_w  = (const float*)d_in[21]; const float* out_b  = (const float*)d_in[22];

    const int N = in_sizes[2];
    const int E = in_sizes[1] / 2;
    const int F = in_sizes[0] / N;       // 128
    const int* src = ei;
    const int* dst = ei + E;
    const int GB64 = (N + 63) / 64;      // node-GEMM grid

    char* w = (char*)d_ws;
    auto alloc = [&](size_t bytes) -> char* {
        char* p = w;
        w += (bytes + 255) & ~(size_t)255;
        return p;
    };
    int*   cnt     = (int*)alloc((size_t)N * 4);
    int*   fillc   = (int*)alloc((size_t)N * 4);
    int*   row_ptr = (int*)alloc((size_t)(N + 1) * 4);
    int*   csr_src = (int*)alloc((size_t)E * 4);
    int*   csr_dst = (int*)alloc((size_t)E * 4);
    float* dinv    = (float*)alloc((size_t)N * 4);
    float* wd      = (float*)alloc((size_t)HD * HD * 4);
    float* act     = (float*)alloc((size_t)N * HD * 4);
    float* hbuf    = (float*)alloc((size_t)N * HD * 4);
    float* Bbuf    = (float*)alloc((size_t)N * HD * 4);
    float* xebuf   = (float*)alloc((size_t)N * HD * 4);
    float* gpool   = (float*)alloc((size_t)64 * 512 * 4);
    // weight packs (bf16 hi/lo, fragment-ordered)
    auto packa = [&](int K) -> __bf16* { return (__bf16*)alloc((size_t)(K / 32) * 8192 * 2); };
    __bf16* pg1h = packa(128); __bf16* pg1l = packa(128);
    __bf16* pg2h = packa(256); __bf16* pg2l = packa(256);
    __bf16* pg3h = packa(256); __bf16* pg3l = packa(256);
    __bf16* pg4h = packa(256); __bf16* pg4l = packa(256);
    __bf16* pe1ah = packa(128); __bf16* pe1al = packa(128);
    __bf16* pe1bh = packa(128); __bf16* pe1bl = packa(128);
    __bf16* pe2ah = packa(256); __bf16* pe2al = packa(256);
    __bf16* pe2bh = packa(256); __bf16* pe2bl = packa(256);
    __bf16* w2h1 = packa(256); __bf16* w2l1 = packa(256);
    __bf16* w2h2 = packa(256); __bf16* w2l2 = packa(256);

    auto wpack = [&](const float* W, __bf16* ph, __bf16* pl, int K){
        int total = (K / 32) * 8192;
        k_wpack<<<(total + 255) / 256, 256, 0, stream>>>(W, ph, pl, K);
    };

    // ---- CSR + deg norm + weight packs ----
    hipMemsetAsync(cnt, 0, (size_t)N * 4, stream);
    hipMemsetAsync(fillc, 0, (size_t)N * 4, stream);
    k_count<<<(E + 255) / 256, 256, 0, stream>>>(dst, cnt, E);
    k_dinv<<<(N + 255) / 256, 256, 0, stream>>>(cnt, dinv, N);
    k_scan<<<1, 1024, 0, stream>>>(cnt, row_ptr, N);
    k_fill<<<(E + 255) / 256, 256, 0, stream>>>(src, dst, row_ptr, fillc, csr_src, csr_dst, E);

    wpack(gcn_w[0], pg1h, pg1l, F);
    wpack(gcn_w[1], pg2h, pg2l, HD);
    wpack(gcn_w[2], pg3h, pg3l, HD);
    wpack(gcn_w[3], pg4h, pg4l, HD);
    k_wdiff<<<(F * HD + 255) / 256, 256, 0, stream>>>(ec1_w1, wd, F);
    wpack(wd, pe1ah, pe1al, F);
    wpack(ec1_w1 + (size_t)F * HD, pe1bh, pe1bl, F);
    k_wdiff<<<(HD * HD + 255) / 256, 256, 0, stream>>>(ec2_w1, wd, HD);
    wpack(wd, pe2ah, pe2al, HD);
    wpack(ec2_w1 + (size_t)HD * HD, pe2bh, pe2bl, HD);
    wpack(ec1_w2, w2h1, w2l1, HD);
    wpack(ec2_w2, w2h2, w2l2, HD);

    // ---- GCN branch ----
    k_gemm_mfma<<<GB64, 256, 0, stream>>>(x, pg1h, pg1l, nullptr, hbuf, N, F);
    k_gcn_agg<<<N / 4, 256, 0, stream>>>(hbuf, dinv, row_ptr, csr_src, gcn_b[0], act, N);
    const __bf16* pgh[3] = {pg2h, pg3h, pg4h};
    const __bf16* pgl[3] = {pg2l, pg3l, pg4l};
    for (int l = 0; l < 3; l++){
        k_gemm_mfma<<<GB64, 256, 0, stream>>>(act, pgh[l], pgl[l], nullptr, hbuf, N, HD);
        k_gcn_agg<<<N / 4, 256, 0, stream>>>(hbuf, dinv, row_ptr, csr_src, gcn_b[l + 1], act, N);
    }

    // ---- EdgeConv 1 (input x, K=F) ----
    k_gemm_mfma<<<GB64, 256, 0, stream>>>(x, pe1ah, pe1al, ec1_b1, hbuf, N, F);   // A = x@(Wt-Wb)+b1
    k_gemm_mfma<<<GB64, 256, 0, stream>>>(x, pe1bh, pe1bl, nullptr, Bbuf, N, F);  // B = x@Wb
    hipMemsetAsync(xebuf, 0, (size_t)N * HD * 4, stream);
    k_edge_mfma<<<E / 64, 256, 0, stream>>>(hbuf, Bbuf, w2h1, w2l1, ec1_b2, csr_src, csr_dst, xebuf, E);

    // ---- EdgeConv 2 (input xe, K=HD) ----
    k_gemm_mfma<<<GB64, 256, 0, stream>>>(xebuf, pe2ah, pe2al, ec2_b1, hbuf, N, HD);
    k_gemm_mfma<<<GB64, 256, 0, stream>>>(xebuf, pe2bh, pe2bl, nullptr, Bbuf, N, HD);
    hipMemsetAsync(xebuf, 0, (size_t)N * HD * 4, stream);
    k_edge_mfma<<<E / 64, 256, 0, stream>>>(hbuf, Bbuf, w2h2, w2l2, ec2_b2, csr_src, csr_dst, xebuf, E);

    // ---- pool + head ----
    k_pool<<<64, 512, 0, stream>>>(act, xebuf, batch, gpool, N);
    k_head<<<64, 256, 0, stream>>>(gpool, fc1_w, fc1_b, out_w, out_b, (float*)d_out);
}

// Round 8
// 1332.282 us; speedup vs baseline: 2.2428x; 1.0843x over previous
//
#include <hip/hip_runtime.h>

#define HD 256   // hidden dim H

typedef __attribute__((ext_vector_type(8))) __bf16 bf16x8;
typedef __attribute__((ext_vector_type(4))) __bf16 bf16x4;
typedef __attribute__((ext_vector_type(4))) float f32x4;

static __device__ __forceinline__ float relu_f(float x){ return x > 0.f ? x : 0.f; }

// split fp32x4 -> bf16 hi/lo
static __device__ __forceinline__ void split4(const float* m, bf16x4& vh, bf16x4& vl){
    #pragma unroll
    for (int j = 0; j < 4; j++){
        float v = m[j];
        __bf16 h = (__bf16)v;
        vh[j] = h;
        vl[j] = (__bf16)(v - (float)h);
    }
}

// ---------------- CSR build ----------------
__global__ void k_count(const int* __restrict__ dst, int* __restrict__ cnt, int E){
    int i = blockIdx.x * blockDim.x + threadIdx.x;
    if (i < E) atomicAdd(&cnt[dst[i]], 1);
}

__global__ void k_dinv(const int* __restrict__ cnt, float* __restrict__ dinv, int n){
    int i = blockIdx.x * blockDim.x + threadIdx.x;
    if (i < n) dinv[i] = 1.0f / sqrtf((float)(cnt[i] + 1));   // +1 self loop
}

// single-block chunked Hillis-Steele exclusive scan
__global__ void k_scan(const int* __restrict__ cnt, int* __restrict__ row_ptr, int n){
    __shared__ int lds[1024];
    int t = threadIdx.x;
    int carry = 0;
    for (int base = 0; base < n; base += 1024){
        int idx = base + t;
        int v = (idx < n) ? cnt[idx] : 0;
        __syncthreads();
        lds[t] = v;
        __syncthreads();
        for (int off = 1; off < 1024; off <<= 1){
            int add = (t >= off) ? lds[t - off] : 0;
            __syncthreads();
            lds[t] += add;
            __syncthreads();
        }
        int incl = lds[t];
        if (idx < n) row_ptr[idx] = carry + incl - v;   // exclusive
        carry += lds[1023];
    }
    if (t == 0) row_ptr[n] = carry;
}

__global__ void k_fill(const int* __restrict__ src, const int* __restrict__ dst,
                       const int* __restrict__ row_ptr, int* __restrict__ fill,
                       int* __restrict__ csr_src, int* __restrict__ csr_dst, int E){
    int i = blockIdx.x * blockDim.x + threadIdx.x;
    if (i < E){
        int d = dst[i];
        int pos = row_ptr[d] + atomicAdd(&fill[d], 1);
        csr_src[pos] = src[i];
        csr_dst[pos] = d;
    }
}

// ---------------- fused weight pack: fragment-ordered bf16 hi/lo, all weights in one launch ----
// Wp[((ks*256 + c)*4 + g)*8 + j] = W[ks*32 + g*8 + j][c]; optional src2 -> pack (src - src2).
struct PackDesc { const float* src; const float* src2; __bf16* ph; __bf16* pl; int K; int pad; };
struct PackArgs { PackDesc d[10]; };

__global__ void k_wpack_all(PackArgs a){
    PackDesc p = a.d[blockIdx.y];
    int total = (p.K >> 5) * 8192;
    int idx = blockIdx.x * 256 + threadIdx.x;
    if (idx >= total) return;
    int j = idx & 7, g = (idx >> 3) & 3, c = (idx >> 5) & 255, ks = idx >> 13;
    int k = ks * 32 + g * 8 + j;
    float v = p.src[(size_t)k * HD + c];
    if (p.src2) v -= p.src2[(size_t)k * HD + c];
    __bf16 h = (__bf16)v;
    p.ph[idx] = h;
    p.pl[idx] = (__bf16)(v - (float)h);
}

// ---------------- MFMA node GEMM: C[M,256] = A[M,K] @ W (+bias) ----------------
// 512 threads / 8 waves; wave w -> cols [32w, 32w+32); acc[4][2] = 32 AGPRs.
// __launch_bounds__(512,4): total regs <= 128 -> 4 waves/SIMD.
__global__ __launch_bounds__(512, 4) void k_gemm_mfma(
    const float* __restrict__ A,
    const __bf16* __restrict__ Wph, const __bf16* __restrict__ Wpl,
    const float* __restrict__ bias,
    float* __restrict__ C, int M, int K)
{
    __shared__ __bf16 mh[2][64][40];   // row stride 80B
    __shared__ __bf16 ml[2][64][40];
    int t = threadIdx.x;
    int m0 = blockIdx.x * 64;
    const int w = t >> 6, fr = t & 15, fg = (t & 63) >> 4;
    const int srow = t >> 3, skb = (t & 7) * 4;      // 8 threads cover 32 k per row
    int ar = m0 + srow; if (ar >= M) ar = M - 1;     // clamp loads; stores guarded
    const float* Arow = A + (size_t)ar * K + skb;
    const int c0 = w * 32 + fr;
    const int KS = K >> 5;

    f32x4 acc[4][2];
    #pragma unroll
    for (int i = 0; i < 4; i++)
        #pragma unroll
        for (int j = 0; j < 2; j++) acc[i][j] = (f32x4){0.f, 0.f, 0.f, 0.f};

    {
        float4 av = *(const float4*)(Arow);
        float m4[4] = {av.x, av.y, av.z, av.w};
        bf16x4 vh, vl;
        split4(m4, vh, vl);
        *(bf16x4*)&mh[0][srow][skb] = vh;
        *(bf16x4*)&ml[0][srow][skb] = vl;
    }

    for (int ks = 0; ks < KS; ++ks){
        float4 av;
        if (ks + 1 < KS) av = *(const float4*)(Arow + (ks + 1) * 32);
        bf16x8 bh[2], bl[2];
        #pragma unroll
        for (int nf = 0; nf < 2; nf++){
            size_t bi = ((size_t)(ks * 256 + c0 + nf * 16) * 4 + fg) * 8;
            bh[nf] = *(const bf16x8*)(Wph + bi);
            bl[nf] = *(const bf16x8*)(Wpl + bi);
        }
        __syncthreads();
        const int cb = ks & 1;
        #pragma unroll
        for (int mf = 0; mf < 4; mf++){
            bf16x8 ah = *(const bf16x8*)&mh[cb][mf * 16 + fr][fg * 8];
            bf16x8 al = *(const bf16x8*)&ml[cb][mf * 16 + fr][fg * 8];
            #pragma unroll
            for (int nf = 0; nf < 2; nf++){
                acc[mf][nf] = __builtin_amdgcn_mfma_f32_16x16x32_bf16(ah, bh[nf], acc[mf][nf], 0, 0, 0);
                acc[mf][nf] = __builtin_amdgcn_mfma_f32_16x16x32_bf16(al, bh[nf], acc[mf][nf], 0, 0, 0);
                acc[mf][nf] = __builtin_amdgcn_mfma_f32_16x16x32_bf16(ah, bl[nf], acc[mf][nf], 0, 0, 0);
            }
        }
        if (ks + 1 < KS){
            float m4[4] = {av.x, av.y, av.z, av.w};
            bf16x4 vh, vl;
            split4(m4, vh, vl);
            *(bf16x4*)&mh[cb ^ 1][srow][skb] = vh;
            *(bf16x4*)&ml[cb ^ 1][srow][skb] = vl;
        }
    }

    float bj[2];
    #pragma unroll
    for (int nf = 0; nf < 2; nf++) bj[nf] = bias ? bias[c0 + nf * 16] : 0.f;
    #pragma unroll
    for (int mf = 0; mf < 4; mf++)
        #pragma unroll
        for (int reg = 0; reg < 4; reg++){
            int row = m0 + mf * 16 + fg * 4 + reg;   // C/D: col=lane&15, row=fg*4+reg (verified)
            if (row < M){
                #pragma unroll
                for (int nf = 0; nf < 2; nf++)
                    C[(size_t)row * HD + c0 + nf * 16] = acc[mf][nf][reg] + bj[nf];
            }
        }
}

// ---------------- GCN aggregate ----------------
__global__ __launch_bounds__(256) void k_gcn_agg(const float* __restrict__ h,
                                                 const float* __restrict__ dinv,
                                                 const int* __restrict__ row_ptr,
                                                 const int* __restrict__ csr_src,
                                                 const float* __restrict__ bias,
                                                 float* __restrict__ out, int n){
    int wid = threadIdx.x >> 6, lane = threadIdx.x & 63;
    int i = blockIdx.x * 4 + wid;
    if (i >= n) return;
    float di = dinv[i];
    const float4* hp = (const float4*)h;
    float4 v = hp[(size_t)i * 64 + lane];
    float ax = v.x * di, ay = v.y * di, az = v.z * di, aw = v.w * di;
    int e0 = row_ptr[i], e1 = row_ptr[i + 1];
    for (int e = e0; e < e1; e++){
        int s = csr_src[e];
        float ds = dinv[s];
        float4 u = hp[(size_t)s * 64 + lane];
        ax += u.x * ds; ay += u.y * ds; az += u.z * ds; aw += u.w * ds;
    }
    const float4 b = ((const float4*)bias)[lane];
    float4 o;
    o.x = relu_f(ax * di + b.x);
    o.y = relu_f(ay * di + b.y);
    o.z = relu_f(az * di + b.z);
    o.w = relu_f(aw * di + b.w);
    ((float4*)out)[(size_t)i * 64 + lane] = o;
}

// ---------------- fused EdgeConv: MFMA edge GEMM + max-aggregate (v3) ----------------
// 512 threads / 8 waves / 32 cols per wave; XCD-bijective block swizzle; dbuf staging;
// run-tracking epilogue with positive-only int-punned atomicMax (out init 0).
__global__ __launch_bounds__(512, 4) void k_edge_mfma(
    const float* __restrict__ A, const float* __restrict__ B,
    const __bf16* __restrict__ Wph, const __bf16* __restrict__ Wpl,
    const float* __restrict__ bias,
    const int* __restrict__ csr_src, const int* __restrict__ csr_dst,
    float* __restrict__ out, int E)
{
    __shared__ __bf16 mh[2][64][40];
    __shared__ __bf16 ml[2][64][40];
    __shared__ int sdst[64], ssrc[64];
    int t = threadIdx.x;
    // XCD-contiguous bijective swizzle (m204): round-robin XCD k gets tile chunk k
    int nwg = gridDim.x;
    int q = nwg >> 3, r = nwg & 7;
    int xc = blockIdx.x & 7;
    int bid = (xc < r ? xc * (q + 1) : r * (q + 1) + (xc - r) * q) + (blockIdx.x >> 3);
    int p0 = bid * 64;
    if (t < 64){
        int e = p0 + t; if (e >= E) e = E - 1;   // duplicate edge: idempotent under max
        sdst[t] = csr_dst[e];
        ssrc[t] = csr_src[e];
    }
    __syncthreads();

    const int w  = t >> 6;
    const int fr = t & 15;
    const int fg = (t & 63) >> 4;
    const int srow = t >> 3, skb = (t & 7) * 4;
    const float* Arow = A + (size_t)sdst[srow] * HD + skb;
    const float* Brow = B + (size_t)ssrc[srow] * HD + skb;
    const int c0 = w * 32 + fr;

    f32x4 acc[4][2];
    #pragma unroll
    for (int i = 0; i < 4; i++)
        #pragma unroll
        for (int j = 0; j < 2; j++) acc[i][j] = (f32x4){0.f, 0.f, 0.f, 0.f};

    {
        float4 a = *(const float4*)(Arow);
        float4 g = *(const float4*)(Brow);
        float m4[4] = {relu_f(a.x + g.x), relu_f(a.y + g.y), relu_f(a.z + g.z), relu_f(a.w + g.w)};
        bf16x4 vh, vl;
        split4(m4, vh, vl);
        *(bf16x4*)&mh[0][srow][skb] = vh;
        *(bf16x4*)&ml[0][srow][skb] = vl;
    }

    for (int ks = 0; ks < 8; ++ks){
        float4 a, g;
        if (ks < 7){                                  // issue next gather early
            a = *(const float4*)(Arow + (ks + 1) * 32);
            g = *(const float4*)(Brow + (ks + 1) * 32);
        }
        bf16x8 bh[2], bl[2];
        #pragma unroll
        for (int nf = 0; nf < 2; nf++){
            size_t bi = ((size_t)(ks * 256 + c0 + nf * 16) * 4 + fg) * 8;
            bh[nf] = *(const bf16x8*)(Wph + bi);
            bl[nf] = *(const bf16x8*)(Wpl + bi);
        }
        __syncthreads();             // buf[ks&1] staged; prev readers of buf[(ks+1)&1] done
        const int cb = ks & 1;
        #pragma unroll
        for (int mf = 0; mf < 4; mf++){
            bf16x8 ah = *(const bf16x8*)&mh[cb][mf * 16 + fr][fg * 8];
            bf16x8 al = *(const bf16x8*)&ml[cb][mf * 16 + fr][fg * 8];
            #pragma unroll
            for (int nf = 0; nf < 2; nf++){
                acc[mf][nf] = __builtin_amdgcn_mfma_f32_16x16x32_bf16(ah, bh[nf], acc[mf][nf], 0, 0, 0);
                acc[mf][nf] = __builtin_amdgcn_mfma_f32_16x16x32_bf16(al, bh[nf], acc[mf][nf], 0, 0, 0);
                acc[mf][nf] = __builtin_amdgcn_mfma_f32_16x16x32_bf16(ah, bl[nf], acc[mf][nf], 0, 0, 0);
            }
        }
        if (ks < 7){
            float m4[4] = {relu_f(a.x + g.x), relu_f(a.y + g.y), relu_f(a.z + g.z), relu_f(a.w + g.w)};
            bf16x4 vh, vl;
            split4(m4, vh, vl);
            *(bf16x4*)&mh[cb ^ 1][srow][skb] = vh;
            *(bf16x4*)&ml[cb ^ 1][srow][skb] = vl;
        }
    }

    // epilogue: run-tracking scan over this thread's 16 rows (sdst non-decreasing in CSR order)
    float bj[2];
    #pragma unroll
    for (int nf = 0; nf < 2; nf++) bj[nf] = bias[c0 + nf * 16];
    int curd = sdst[fg * 4];
    float v[2];
    #pragma unroll
    for (int nf = 0; nf < 2; nf++) v[nf] = acc[0][nf][0] + bj[nf];
    #pragma unroll
    for (int mf = 0; mf < 4; mf++){
        #pragma unroll
        for (int reg = 0; reg < 4; reg++){
            if (mf == 0 && reg == 0) continue;
            int d = sdst[mf * 16 + fg * 4 + reg];
            if (d != curd){
                #pragma unroll
                for (int nf = 0; nf < 2; nf++)
                    if (v[nf] > 0.f)
                        atomicMax((int*)(out + (size_t)curd * HD + c0 + nf * 16), __float_as_int(v[nf]));
                curd = d;
                #pragma unroll
                for (int nf = 0; nf < 2; nf++) v[nf] = acc[mf][nf][reg] + bj[nf];
            } else {
                #pragma unroll
                for (int nf = 0; nf < 2; nf++) v[nf] = fmaxf(v[nf], acc[mf][nf][reg] + bj[nf]);
            }
        }
    }
    #pragma unroll
    for (int nf = 0; nf < 2; nf++)
        if (v[nf] > 0.f)
            atomicMax((int*)(out + (size_t)curd * HD + c0 + nf * 16), __float_as_int(v[nf]));
}

// ---------------- per-graph sum pool ----------------
__global__ __launch_bounds__(512) void k_pool(const float* __restrict__ xg,
                                              const float* __restrict__ xe,
                                              const int* __restrict__ batch,
                                              float* __restrict__ gpool, int n){
    int g = blockIdx.x, t = threadIdx.x;
    int lo, hi;
    { int l = 0, h = n; while (l < h){ int m = (l + h) >> 1; if (batch[m] < g) l = m + 1; else h = m; } lo = l; }
    { int l = lo, h = n; while (l < h){ int m = (l + h) >> 1; if (batch[m] < g + 1) l = m + 1; else h = m; } hi = l; }
    const float* sp = (t < 256) ? (xg + t) : (xe + (t - 256));
    float a0 = 0.f, a1 = 0.f;
    int i = lo;
    for (; i + 1 < hi; i += 2){
        a0 += sp[(size_t)i * HD];
        a1 += sp[(size_t)(i + 1) * HD];
    }
    if (i < hi) a0 += sp[(size_t)i * HD];
    gpool[g * 512 + t] = a0 + a1;
}

// ---------------- head ----------------
__global__ __launch_bounds__(256) void k_head(const float* __restrict__ gpool,
                                              const float* __restrict__ w1,
                                              const float* __restrict__ b1,
                                              const float* __restrict__ w2,
                                              const float* __restrict__ b2,
                                              float* __restrict__ out){
    __shared__ float red[256];
    int g = blockIdx.x, t = threadIdx.x;
    float acc = b1[t];
    const float* gp = gpool + g * 512;
    #pragma unroll 4
    for (int k = 0; k < 512; k++) acc += gp[k] * w1[k * HD + t];
    red[t] = relu_f(acc) * w2[t];
    __syncthreads();
    for (int s = 128; s > 0; s >>= 1){
        if (t < s) red[t] += red[t + s];
        __syncthreads();
    }
    if (t == 0) out[g] = red[0] + b2[0];
}

extern "C" void kernel_launch(void* const* d_in, const int* in_sizes, int n_in,
                              void* d_out, int out_size, void* d_ws, size_t ws_size,
                              hipStream_t stream){
    const float* x      = (const float*)d_in[0];
    const int*   ei     = (const int*)d_in[1];
    const int*   batch  = (const int*)d_in[2];
    const float* gcn_w[4] = {(const float*)d_in[3], (const float*)d_in[5], (const float*)d_in[7], (const float*)d_in[9]};
    const float* gcn_b[4] = {(const float*)d_in[4], (const float*)d_in[6], (const float*)d_in[8], (const float*)d_in[10]};
    const float* ec1_w1 = (const float*)d_in[11]; const float* ec1_b1 = (const float*)d_in[12];
    const float* ec1_w2 = (const float*)d_in[13]; const float* ec1_b2 = (const float*)d_in[14];
    const float* ec2_w1 = (const float*)d_in[15]; const float* ec2_b1 = (const float*)d_in[16];
    const float* ec2_w2 = (const float*)d_in[17]; const float* ec2_b2 = (const float*)d_in[18];
    const float* fc1_w  = (const float*)d_in[19]; const float* fc1_b  = (const float*)d_in[20];
    const float* out_w  = (const float*)d_in[21]; const float* out_b  = (const float*)d_in[22];

    const int N = in_sizes[2];
    const int E = in_sizes[1] / 2;
    const int F = in_sizes[0] / N;       // 128
    const int* src = ei;
    const int* dst = ei + E;
    const int GB64 = (N + 63) / 64;      // node-GEMM grid
    const int EB   = (E + 63) / 64;      // edge grid

    char* w = (char*)d_ws;
    auto alloc = [&](size_t bytes) -> char* {
        char* p = w;
        w += (bytes + 255) & ~(size_t)255;
        return p;
    };
    int*   cnt     = (int*)alloc((size_t)N * 4);
    int*   fillc   = (int*)alloc((size_t)N * 4);
    int*   row_ptr = (int*)alloc((size_t)(N + 1) * 4);
    int*   csr_src = (int*)alloc((size_t)E * 4);
    int*   csr_dst = (int*)alloc((size_t)E * 4);
    float* dinv    = (float*)alloc((size_t)N * 4);
    float* act     = (float*)alloc((size_t)N * HD * 4);
    float* hbuf    = (float*)alloc((size_t)N * HD * 4);
    float* Bbuf    = (float*)alloc((size_t)N * HD * 4);
    float* xebuf   = (float*)alloc((size_t)N * HD * 4);
    float* gpool   = (float*)alloc((size_t)64 * 512 * 4);
    // weight packs (bf16 hi/lo, fragment-ordered)
    auto packa = [&](int K) -> __bf16* { return (__bf16*)alloc((size_t)K * 256 * 2); };
    __bf16* pg1h = packa(128); __bf16* pg1l = packa(128);
    __bf16* pg2h = packa(256); __bf16* pg2l = packa(256);
    __bf16* pg3h = packa(256); __bf16* pg3l = packa(256);
    __bf16* pg4h = packa(256); __bf16* pg4l = packa(256);
    __bf16* pe1ah = packa(128); __bf16* pe1al = packa(128);
    __bf16* pe1bh = packa(128); __bf16* pe1bl = packa(128);
    __bf16* pe2ah = packa(256); __bf16* pe2al = packa(256);
    __bf16* pe2bh = packa(256); __bf16* pe2bl = packa(256);
    __bf16* w2h1 = packa(256); __bf16* w2l1 = packa(256);
    __bf16* w2h2 = packa(256); __bf16* w2l2 = packa(256);

    // ---- CSR + deg norm ----
    hipMemsetAsync(cnt, 0, (size_t)N * 4, stream);
    hipMemsetAsync(fillc, 0, (size_t)N * 4, stream);
    k_count<<<(E + 255) / 256, 256, 0, stream>>>(dst, cnt, E);
    k_dinv<<<(N + 255) / 256, 256, 0, stream>>>(cnt, dinv, N);
    k_scan<<<1, 1024, 0, stream>>>(cnt, row_ptr, N);
    k_fill<<<(E + 255) / 256, 256, 0, stream>>>(src, dst, row_ptr, fillc, csr_src, csr_dst, E);

    // ---- all weight packs in ONE launch (wdiff folded in via src2) ----
    PackArgs pa;
    pa.d[0] = {gcn_w[0],                  nullptr,                    pg1h,  pg1l,  F,  0};
    pa.d[1] = {gcn_w[1],                  nullptr,                    pg2h,  pg2l,  HD, 0};
    pa.d[2] = {gcn_w[2],                  nullptr,                    pg3h,  pg3l,  HD, 0};
    pa.d[3] = {gcn_w[3],                  nullptr,                    pg4h,  pg4l,  HD, 0};
    pa.d[4] = {ec1_w1,                    ec1_w1 + (size_t)F * HD,    pe1ah, pe1al, F,  0};
    pa.d[5] = {ec1_w1 + (size_t)F * HD,   nullptr,                    pe1bh, pe1bl, F,  0};
    pa.d[6] = {ec2_w1,                    ec2_w1 + (size_t)HD * HD,   pe2ah, pe2al, HD, 0};
    pa.d[7] = {ec2_w1 + (size_t)HD * HD,  nullptr,                    pe2bh, pe2bl, HD, 0};
    pa.d[8] = {ec1_w2,                    nullptr,                    w2h1,  w2l1,  HD, 0};
    pa.d[9] = {ec2_w2,                    nullptr,                    w2h2,  w2l2,  HD, 0};
    k_wpack_all<<<dim3(256, 10), 256, 0, stream>>>(pa);

    // ---- GCN branch ----
    k_gemm_mfma<<<GB64, 512, 0, stream>>>(x, pg1h, pg1l, nullptr, hbuf, N, F);
    k_gcn_agg<<<(N + 3) / 4, 256, 0, stream>>>(hbuf, dinv, row_ptr, csr_src, gcn_b[0], act, N);
    const __bf16* pgh[3] = {pg2h, pg3h, pg4h};
    const __bf16* pgl[3] = {pg2l, pg3l, pg4l};
    for (int l = 0; l < 3; l++){
        k_gemm_mfma<<<GB64, 512, 0, stream>>>(act, pgh[l], pgl[l], nullptr, hbuf, N, HD);
        k_gcn_agg<<<(N + 3) / 4, 256, 0, stream>>>(hbuf, dinv, row_ptr, csr_src, gcn_b[l + 1], act, N);
    }

    // ---- EdgeConv 1 (input x, K=F) ----
    k_gemm_mfma<<<GB64, 512, 0, stream>>>(x, pe1ah, pe1al, ec1_b1, hbuf, N, F);   // A = x@(Wt-Wb)+b1
    k_gemm_mfma<<<GB64, 512, 0, stream>>>(x, pe1bh, pe1bl, nullptr, Bbuf, N, F);  // B = x@Wb
    hipMemsetAsync(xebuf, 0, (size_t)N * HD * 4, stream);
    k_edge_mfma<<<EB, 512, 0, stream>>>(hbuf, Bbuf, w2h1, w2l1, ec1_b2, csr_src, csr_dst, xebuf, E);

    // ---- EdgeConv 2 (input xe, K=HD) ----
    k_gemm_mfma<<<GB64, 512, 0, stream>>>(xebuf, pe2ah, pe2al, ec2_b1, hbuf, N, HD);
    k_gemm_mfma<<<GB64, 512, 0, stream>>>(xebuf, pe2bh, pe2bl, nullptr, Bbuf, N, HD);
    hipMemsetAsync(xebuf, 0, (size_t)N * HD * 4, stream);
    k_edge_mfma<<<EB, 512, 0, stream>>>(hbuf, Bbuf, w2h2, w2l2, ec2_b2, csr_src, csr_dst, xebuf, E);

    // ---- pool + head ----
    k_pool<<<64, 512, 0, stream>>>(act, xebuf, batch, gpool, N);
    k_head<<<64, 256, 0, stream>>>(gpool, fc1_w, fc1_b, out_w, out_b, (float*)d_out);
}